// Round 9
// baseline (1699.365 us; speedup 1.0000x reference)
//
#include <hip/hip_runtime.h>
#include <math.h>

// Problem constants (match reference)
constexpr int Bn = 4, Cn = 12, Hn = 256, Wn = 256;
constexpr int HWn  = Hn * Wn;        // 65536
constexpr int NPIX = Bn * HWn;       // 262144
constexpr int NPLANE = Bn * Cn;      // 48 (b,c) planes
constexpr int NMASK = 2 * NPLANE;    // 96 masks (48 pred + 48 target)
constexpr int NJOB  = 2 * NMASK;     // 192 EDT jobs (edt(mask), edt(~mask))
constexpr float LARGEf = 1.0e6f;
constexpr unsigned short SENT = 65535;

// fgflags layout: [0..3] = pred fg bitmask per batch (bit c), [4..7] = tgt fg

// ---------------------------------------------------------------------------
// Kernel A: per-pixel softmax -> bit-packed masks word (bits 0..11 pred>0.5,
// bits 12..23 target one-hot), err = (prob-onehot)^2 per channel, CE partial
// per wave, per-wave OR word plain-stored (no contended atomics).
// Also re-zeroes the rowpass ticket (runs strictly before rowpass).
// ---------------------------------------------------------------------------
__global__ void masks_kernel(const float* __restrict__ pred,
                             const int* __restrict__ target,
                             unsigned int* __restrict__ maskw,
                             float* __restrict__ err,
                             unsigned int* __restrict__ blockOr,
                             double* __restrict__ cepart,
                             unsigned int* __restrict__ ticket) {
    if (blockIdx.x == 0 && threadIdx.x == 0) *ticket = 0u;
    int pix = blockIdx.x * blockDim.x + threadIdx.x;   // grid = NPIX exactly
    int b = pix >> 16;            // / HW (each block lies within one b)
    int p = pix & (HWn - 1);
    float v[Cn];
    float mx = -3.4e38f;
#pragma unroll
    for (int c = 0; c < Cn; ++c) {
        v[c] = pred[(size_t)(b * Cn + c) * HWn + p];
        mx = fmaxf(mx, v[c]);
    }
    int t = target[pix];
    float raw_t = 0.f, s = 0.f;
#pragma unroll
    for (int c = 0; c < Cn; ++c) {
        if (c == t) raw_t = v[c];
        v[c] = expf(v[c] - mx);
        s += v[c];
    }
    unsigned word = 1u << (Cn + t);   // target one-hot bit
#pragma unroll
    for (int c = 0; c < Cn; ++c) {
        float prob = v[c] / s;
        int pb = (prob > 0.5f) ? 1 : 0;
        word |= (unsigned)pb << c;
        float oh = (c == t) ? 1.0f : 0.0f;
        float d = prob - oh;
        err[(size_t)(b * Cn + c) * HWn + p] = d * d;
    }
    maskw[pix] = word;
    float logp_t = raw_t - mx - logf(s);

    // wave-level OR + CE sum (no barriers), one plain store per wave
    unsigned worw = word;
    for (int o = 32; o > 0; o >>= 1) worw |= __shfl_down(worw, o, 64);
    double ced = (double)logp_t;
    for (int o = 32; o > 0; o >>= 1) ced += __shfl_down(ced, o, 64);
    int lane = threadIdx.x & 63, wv = threadIdx.x >> 6;
    if (lane == 0) {
        blockOr[blockIdx.x * 4 + wv] = worw;   // plain store, zero contention
        cepart[blockIdx.x * 4 + wv] = ced;
    }
}

__device__ __forceinline__ int mask_has_fg(const unsigned int* fgflags, int m) {
    int mm = (m < NPLANE) ? m : m - NPLANE;
    int b = mm / Cn, c = mm % Cn;
    unsigned fg = (m < NPLANE) ? fgflags[b] : fgflags[4 + b];
    return (fg >> c) & 1;
}

// ---------------------------------------------------------------------------
// Kernel C: segmented column pass (UNGATED - empty planes compute real
// values; rowpass gates correctness). Block NJOB*SEG does the fgflags
// reduction instead (no other block reads fgflags -> no race).
// ---------------------------------------------------------------------------
constexpr int SEG  = 4;
constexpr int SEGR = Hn / SEG;   // 64
constexpr int STRb = 68;         // LDS byte stride per thread (17 words, coprime banks)

__global__ void colpass_kernel(const unsigned int* __restrict__ maskw,
                               const unsigned int* __restrict__ blockOr,
                               unsigned short* __restrict__ gcol,
                               unsigned int* __restrict__ fgflags) {
    int blk = blockIdx.x;         // 0..768
    int tid = threadIdx.x;
    int lane = tid & 63, wv = tid >> 6;
    if (blk == NJOB * SEG) {
        // reduce 4096 per-wave OR words -> 8 fgflags words; one wave per batch
        unsigned acc = 0;
#pragma unroll
        for (int k = 0; k < 16; ++k) acc |= blockOr[wv * 1024 + k * 64 + lane];
        for (int o = 32; o > 0; o >>= 1) acc |= __shfl_down(acc, o, 64);
        if (lane == 0) {
            fgflags[wv] = acc & 0xFFFu;
            fgflags[4 + wv] = acc >> Cn;
        }
        return;
    }
    int jb = blk >> 2;            // job 0..191
    int cg = blk & 3;             // column group
    int m  = (jb < NMASK) ? jb : jb - NMASK;
    int mm = (m < NPLANE) ? m : m - NPLANE;
    int b = mm / Cn, c = mm % Cn;
    unsigned bit = (m < NPLANE) ? (unsigned)c : (unsigned)(Cn + c);
    unsigned inv = (jb < NMASK) ? 1u : 0u;  // feature = !maskbit for edt(mask)
    int s  = wv;                  // segment 0..3 (uniform per wave)
    int jl = lane;
    int j  = cg * 64 + jl;
    int r0 = s * SEGR;
    const unsigned int* mp = maskw + (size_t)b * HWn;
    unsigned short* gp = gcol + (size_t)jb * HWn;

    __shared__ unsigned char ldsF[256 * STRb];
    __shared__ unsigned char ldsB[256 * STRb];
    __shared__ float eF[256], eB[256];

    unsigned b0 = 0, b1 = 0;
    float cd = LARGEf;
    for (int i = 0; i < SEGR; ++i) {
        unsigned w = mp[(r0 + i) * Wn + j];
        unsigned f = ((w >> bit) & 1u) ^ inv;
        if (i < 32) b0 |= f << i; else b1 |= f << (i - 32);
        cd = f ? 0.f : fminf(cd + 1.f, LARGEf);
        ldsF[tid * STRb + i] = (unsigned char)fminf(cd, 255.f);   // <=63 or 255
    }
    eF[tid] = cd;
    cd = LARGEf;
    for (int i = SEGR - 1; i >= 0; --i) {
        unsigned f = ((i < 32) ? (b0 >> i) : (b1 >> (i - 32))) & 1u;
        cd = f ? 0.f : fminf(cd + 1.f, LARGEf);
        ldsB[tid * STRb + i] = (unsigned char)fminf(cd, 255.f);
    }
    eB[tid] = cd;
    __syncthreads();
    float x = LARGEf;                         // fwd inflow to my segment
    for (int sp = 0; sp < s; ++sp)
        x = fminf(eF[sp * 64 + jl], fminf(x + (float)SEGR, LARGEf));
    float y = LARGEf;                         // bwd inflow from below
    for (int sp = SEG - 1; sp > s; --sp)
        y = fminf(eB[sp * 64 + jl], fminf(y + (float)SEGR, LARGEf));
#pragma unroll 8
    for (int i = 0; i < SEGR; ++i) {
        unsigned char uf = ldsF[tid * STRb + i];
        unsigned char ub = ldsB[tid * STRb + i];
        float lf = (uf == 255u) ? LARGEf : (float)uf;
        float lb = (ub == 255u) ? LARGEf : (float)ub;
        float f = fminf(lf, fminf(x + (float)(i + 1), LARGEf));
        float w = fminf(lb, fminf(y + (float)(SEGR - i), LARGEf));
        float g = fminf(f, w);
        gp[(r0 + i) * Wn + j] = (g >= LARGEf) ? SENT : (unsigned short)g;
    }
}

// ---------------------------------------------------------------------------
// Kernel D: row pass fused with loss accumulation AND final reduction via
// last-block-done ticket. Outward scan split per polarity, X-padded
// unconditional loads (exact), per-wave shfl f64 reduce (no post-scan
// barriers on the hot path). Last ticket holder reduces all partials in a
// FIXED order (deterministic) and writes the scalar output.
// ---------------------------------------------------------------------------
constexpr int RPAD = 256;
constexpr int NROWBLK = NMASK * Hn;   // 24576

__device__ __forceinline__ float outward_min(const float* __restrict__ r,
                                             int j, float m0) {
    const float* pl = r + RPAD + j;
    float k2 = 1.f;                    // k^2
    for (int k = 1; k < Wn; k += 2) {
        if (k2 >= m0) break;
        float k2b = k2 + (float)(2 * k + 1);   // (k+1)^2
        m0 = fminf(m0, k2  + pl[-k]);
        m0 = fminf(m0, k2  + pl[k]);
        m0 = fminf(m0, k2b + pl[-k - 1]);
        m0 = fminf(m0, k2b + pl[k + 1]);
        k2 = k2b + (float)(2 * k + 3);         // (k+2)^2
    }
    return m0;
}

__global__ void rowpass_kernel(const unsigned short* __restrict__ gcol,
                               const float* __restrict__ err,
                               const unsigned int* __restrict__ fgflags,
                               double* __restrict__ partials,
                               const double* __restrict__ cepart,
                               unsigned int* __restrict__ ticket,
                               float* __restrict__ out) {
    int blk = blockIdx.x;             // 0 .. NROWBLK-1
    int m = blk >> 8;                 // mask plane 0..95
    int i = blk & (Hn - 1);           // row
    int j = threadIdx.x;              // col
    __shared__ float rA[Wn + 2 * RPAD];
    __shared__ float rB[Wn + 2 * RPAD];
    if (mask_has_fg(fgflags, m)) {
        const float X = 1e12f;        // == fl(1e6f*1e6f)
        const unsigned short* rp = gcol + (size_t)m * HWn + i * Wn;            // edt(mask)
        const unsigned short* rq = gcol + (size_t)(m + NMASK) * HWn + i * Wn;  // edt(~mask)
        unsigned short ua = rp[j], ub = rq[j];
        float a  = (ua == SENT) ? X : (float)((int)ua * (int)ua);
        float bb = (ub == SENT) ? X : (float)((int)ub * (int)ub);
        rA[j] = X; rA[RPAD + Wn + j] = X; rA[RPAD + j] = a;
        rB[j] = X; rB[RPAD + Wn + j] = X; rB[RPAD + j] = bb;
        __syncthreads();
        float m0 = outward_min(rA, j, a);
        float m1 = outward_min(rB, j, bb);
        float f = sqrtf(m0) + sqrtf(m1);  // field value at (m, i, j)
        int ep = (m < NPLANE) ? m : m - NPLANE;
        float e = err[(size_t)ep * HWn + i * Wn + j];
        double v = (double)(e * (f * f));
        for (int o = 32; o > 0; o >>= 1) v += __shfl_down(v, o, 64);
        if ((j & 63) == 0) partials[blk * 4 + (j >> 6)] = v;
    } else {
        if (j < 4) partials[blk * 4 + j] = 0.0;   // plane zeroed by loss gating
    }

    // ---- last-block-done final reduction (deterministic fixed-order sum) ---
    __threadfence();                  // release partials device-wide
    __shared__ unsigned lastdone;
    if (j == 0) lastdone = (atomicAdd(ticket, 1u) == (unsigned)(NROWBLK - 1)) ? 1u : 0u;
    __syncthreads();
    if (!lastdone) return;
    __threadfence();                  // acquire other blocks' partials
    double a = 0.0, ce = 0.0;
    for (int idx = j; idx < NROWBLK * 4; idx += 256) a += partials[idx];
    for (int idx = j; idx < 4096; idx += 256) ce += cepart[idx];
    __shared__ double sa[256], sc[256];
    sa[j] = a; sc[j] = ce;
    __syncthreads();
    for (int s = 128; s > 0; s >>= 1) {
        if (j < s) { sa[j] += sa[j + s]; sc[j] += sc[j + s]; }
        __syncthreads();
    }
    if (j == 0) {
        double loss_sum = sa[0] / (double)NPIX;        // sum_c mean_{b,h,w}
        double cem = -sc[0] / (double)NPIX;            // ce
        out[0] = (float)(loss_sum / (double)Cn / (double)Bn / 3.0 + cem);
    }
}

// ---------------------------------------------------------------------------
extern "C" void kernel_launch(void* const* d_in, const int* in_sizes, int n_in,
                              void* d_out, int out_size, void* d_ws, size_t ws_size,
                              hipStream_t stream) {
    const float* pred  = (const float*)d_in[0];
    const int* target  = (const int*)d_in[1];
    float* out = (float*)d_out;
    char* ws = (char*)d_ws;

    // workspace layout (~40 MB total)
    unsigned int* maskw = (unsigned int*)ws;                         // 1 MB
    size_t off = (size_t)NPIX * 4;
    float* err = (float*)(ws + off);                                 // 12.6 MB
    off += (size_t)NPLANE * HWn * 4;
    unsigned short* gcol = (unsigned short*)(ws + off);              // 25.2 MB
    off += (size_t)NJOB * HWn * 2;
    unsigned int* fgflags = (unsigned int*)(ws + off);               // 8 u32 (pad 512)
    off += 512;
    unsigned int* blockOr = (unsigned int*)(ws + off);               // 4096*4
    off += 4096 * 4;
    double* partials = (double*)(ws + off);                          // 98304*8
    off += (size_t)NROWBLK * 4 * 8;
    double* cepart = (double*)(ws + off);                            // 4096*8
    off += 4096 * 8;
    unsigned int* ticket = (unsigned int*)(ws + off);                // 1 u32

    masks_kernel<<<NPIX / 256, 256, 0, stream>>>(pred, target, maskw, err,
                                                 blockOr, cepart, ticket);
    colpass_kernel<<<NJOB * SEG + 1, 256, 0, stream>>>(maskw, blockOr, gcol, fgflags);
    rowpass_kernel<<<NROWBLK, 256, 0, stream>>>(gcol, err, fgflags, partials,
                                                cepart, ticket, out);
}

// Round 10
// 101.349 us; speedup vs baseline: 16.7674x; 16.7674x over previous
//
#include <hip/hip_runtime.h>
#include <math.h>

// Problem constants (match reference)
constexpr int Bn = 4, Cn = 12, Hn = 256, Wn = 256;
constexpr int HWn  = Hn * Wn;        // 65536
constexpr int NPIX = Bn * HWn;       // 262144
constexpr int NPLANE = Bn * Cn;      // 48 (b,c) planes
constexpr int NMASK = 2 * NPLANE;    // 96 masks (48 pred + 48 target)
constexpr int NJOB  = 2 * NMASK;     // 192 EDT jobs (edt(mask), edt(~mask))
constexpr float LARGEf = 1.0e6f;
constexpr unsigned short SENT = 65535;

// fgflags layout: [0..3] = pred fg bitmask per batch (bit c), [4..7] = tgt fg

// ---------------------------------------------------------------------------
// Kernel A: per-pixel softmax -> bit-packed masks word (bits 0..11 pred>0.5,
// bits 12..23 target one-hot), err = (prob-onehot)^2 per channel, CE partial
// per wave, per-wave OR word plain-stored (no contended atomics).
// ---------------------------------------------------------------------------
__global__ void masks_kernel(const float* __restrict__ pred,
                             const int* __restrict__ target,
                             unsigned int* __restrict__ maskw,
                             float* __restrict__ err,
                             unsigned int* __restrict__ blockOr,
                             double* __restrict__ cepart) {
    int pix = blockIdx.x * blockDim.x + threadIdx.x;   // grid = NPIX exactly
    int b = pix >> 16;            // / HW (each block lies within one b)
    int p = pix & (HWn - 1);
    float v[Cn];
    float mx = -3.4e38f;
#pragma unroll
    for (int c = 0; c < Cn; ++c) {
        v[c] = pred[(size_t)(b * Cn + c) * HWn + p];
        mx = fmaxf(mx, v[c]);
    }
    int t = target[pix];
    float raw_t = 0.f, s = 0.f;
#pragma unroll
    for (int c = 0; c < Cn; ++c) {
        if (c == t) raw_t = v[c];
        v[c] = expf(v[c] - mx);
        s += v[c];
    }
    unsigned word = 1u << (Cn + t);   // target one-hot bit
#pragma unroll
    for (int c = 0; c < Cn; ++c) {
        float prob = v[c] / s;
        int pb = (prob > 0.5f) ? 1 : 0;
        word |= (unsigned)pb << c;
        float oh = (c == t) ? 1.0f : 0.0f;
        float d = prob - oh;
        err[(size_t)(b * Cn + c) * HWn + p] = d * d;
    }
    maskw[pix] = word;
    float logp_t = raw_t - mx - logf(s);

    // wave-level OR + CE sum (no barriers), one plain store per wave
    unsigned worw = word;
    for (int o = 32; o > 0; o >>= 1) worw |= __shfl_down(worw, o, 64);
    double ced = (double)logp_t;
    for (int o = 32; o > 0; o >>= 1) ced += __shfl_down(ced, o, 64);
    int lane = threadIdx.x & 63, wv = threadIdx.x >> 6;
    if (lane == 0) {
        blockOr[blockIdx.x * 4 + wv] = worw;   // plain store, zero contention
        cepart[blockIdx.x * 4 + wv] = ced;
    }
}

__device__ __forceinline__ int mask_has_fg(const unsigned int* fgflags, int m) {
    int mm = (m < NPLANE) ? m : m - NPLANE;
    int b = mm / Cn, c = mm % Cn;
    unsigned fg = (m < NPLANE) ? fgflags[b] : fgflags[4 + b];
    return (fg >> c) & 1;
}

// ---------------------------------------------------------------------------
// Kernel C: segmented column pass (UNGATED - empty planes compute real
// values; rowpass gates correctness). Block NJOB*SEG does the fgflags
// reduction instead (no other block reads fgflags -> no race; stream order
// guarantees masks_kernel finished).
// ---------------------------------------------------------------------------
constexpr int SEG  = 4;
constexpr int SEGR = Hn / SEG;   // 64
constexpr int STRb = 68;         // LDS byte stride per thread (17 words, coprime banks)

__global__ void colpass_kernel(const unsigned int* __restrict__ maskw,
                               const unsigned int* __restrict__ blockOr,
                               unsigned short* __restrict__ gcol,
                               unsigned int* __restrict__ fgflags) {
    int blk = blockIdx.x;         // 0..768
    int tid = threadIdx.x;
    int lane = tid & 63, wv = tid >> 6;
    if (blk == NJOB * SEG) {
        // reduce 4096 per-wave OR words -> 8 fgflags words; one wave per batch
        unsigned acc = 0;
#pragma unroll
        for (int k = 0; k < 16; ++k) acc |= blockOr[wv * 1024 + k * 64 + lane];
        for (int o = 32; o > 0; o >>= 1) acc |= __shfl_down(acc, o, 64);
        if (lane == 0) {
            fgflags[wv] = acc & 0xFFFu;
            fgflags[4 + wv] = acc >> Cn;
        }
        return;
    }
    int jb = blk >> 2;            // job 0..191
    int cg = blk & 3;             // column group
    int m  = (jb < NMASK) ? jb : jb - NMASK;
    int mm = (m < NPLANE) ? m : m - NPLANE;
    int b = mm / Cn, c = mm % Cn;
    unsigned bit = (m < NPLANE) ? (unsigned)c : (unsigned)(Cn + c);
    unsigned inv = (jb < NMASK) ? 1u : 0u;  // feature = !maskbit for edt(mask)
    int s  = wv;                  // segment 0..3 (uniform per wave)
    int jl = lane;
    int j  = cg * 64 + jl;
    int r0 = s * SEGR;
    const unsigned int* mp = maskw + (size_t)b * HWn;
    unsigned short* gp = gcol + (size_t)jb * HWn;

    __shared__ unsigned char ldsF[256 * STRb];
    __shared__ unsigned char ldsB[256 * STRb];
    __shared__ float eF[256], eB[256];

    unsigned b0 = 0, b1 = 0;
    float cd = LARGEf;
    for (int i = 0; i < SEGR; ++i) {
        unsigned w = mp[(r0 + i) * Wn + j];
        unsigned f = ((w >> bit) & 1u) ^ inv;
        if (i < 32) b0 |= f << i; else b1 |= f << (i - 32);
        cd = f ? 0.f : fminf(cd + 1.f, LARGEf);
        ldsF[tid * STRb + i] = (unsigned char)fminf(cd, 255.f);   // <=63 or 255
    }
    eF[tid] = cd;
    cd = LARGEf;
    for (int i = SEGR - 1; i >= 0; --i) {
        unsigned f = ((i < 32) ? (b0 >> i) : (b1 >> (i - 32))) & 1u;
        cd = f ? 0.f : fminf(cd + 1.f, LARGEf);
        ldsB[tid * STRb + i] = (unsigned char)fminf(cd, 255.f);
    }
    eB[tid] = cd;
    __syncthreads();
    float x = LARGEf;                         // fwd inflow to my segment
    for (int sp = 0; sp < s; ++sp)
        x = fminf(eF[sp * 64 + jl], fminf(x + (float)SEGR, LARGEf));
    float y = LARGEf;                         // bwd inflow from below
    for (int sp = SEG - 1; sp > s; --sp)
        y = fminf(eB[sp * 64 + jl], fminf(y + (float)SEGR, LARGEf));
#pragma unroll 8
    for (int i = 0; i < SEGR; ++i) {
        unsigned char uf = ldsF[tid * STRb + i];
        unsigned char ub = ldsB[tid * STRb + i];
        float lf = (uf == 255u) ? LARGEf : (float)uf;
        float lb = (ub == 255u) ? LARGEf : (float)ub;
        float f = fminf(lf, fminf(x + (float)(i + 1), LARGEf));
        float w = fminf(lb, fminf(y + (float)(SEGR - i), LARGEf));
        float g = fminf(f, w);
        gp[(r0 + i) * Wn + j] = (g >= LARGEf) ? SENT : (unsigned short)g;
    }
}

// ---------------------------------------------------------------------------
// Kernel D: row pass fused with loss accumulation. Outward scan, split per
// polarity, 256-elem X=fl(1e12) padding (unconditional loads; padded
// candidates can never lower the min -> exact). 2-wide unrolled break check.
// Epilogue: per-wave __shfl_down f64 reduction, plain partial stores, NO
// fences/atomics (R9 lesson: per-block threadfence+atomic = 68 ns x 24576).
// ---------------------------------------------------------------------------
constexpr int RPAD = 256;
constexpr int NROWBLK = NMASK * Hn;   // 24576

__device__ __forceinline__ float outward_min(const float* __restrict__ r,
                                             int j, float m0) {
    const float* pl = r + RPAD + j;
    float k2 = 1.f;                    // k^2
    for (int k = 1; k < Wn; k += 2) {
        if (k2 >= m0) break;
        float k2b = k2 + (float)(2 * k + 1);   // (k+1)^2
        m0 = fminf(m0, k2  + pl[-k]);
        m0 = fminf(m0, k2  + pl[k]);
        m0 = fminf(m0, k2b + pl[-k - 1]);
        m0 = fminf(m0, k2b + pl[k + 1]);
        k2 = k2b + (float)(2 * k + 3);         // (k+2)^2
    }
    return m0;
}

__global__ void rowpass_kernel(const unsigned short* __restrict__ gcol,
                               const float* __restrict__ err,
                               const unsigned int* __restrict__ fgflags,
                               double* __restrict__ partials) {
    int blk = blockIdx.x;             // 0 .. NROWBLK-1
    int m = blk >> 8;                 // mask plane 0..95
    int i = blk & (Hn - 1);           // row
    int j = threadIdx.x;              // col
    if (!mask_has_fg(fgflags, m)) {
        if (j < 4) partials[blk * 4 + j] = 0.0;   // plane zeroed by loss gating
        return;
    }
    const float X = 1e12f;            // == fl(1e6f*1e6f)
    __shared__ float rA[Wn + 2 * RPAD];
    __shared__ float rB[Wn + 2 * RPAD];
    const unsigned short* rp = gcol + (size_t)m * HWn + i * Wn;            // edt(mask)
    const unsigned short* rq = gcol + (size_t)(m + NMASK) * HWn + i * Wn;  // edt(~mask)
    unsigned short ua = rp[j], ub = rq[j];
    float a  = (ua == SENT) ? X : (float)((int)ua * (int)ua);
    float bb = (ub == SENT) ? X : (float)((int)ub * (int)ub);
    rA[j] = X; rA[RPAD + Wn + j] = X; rA[RPAD + j] = a;
    rB[j] = X; rB[RPAD + Wn + j] = X; rB[RPAD + j] = bb;
    __syncthreads();                  // the ONLY barrier in this kernel
    float m0 = outward_min(rA, j, a);
    float m1 = outward_min(rB, j, bb);
    float f = sqrtf(m0) + sqrtf(m1);  // field value at (m, i, j)
    int ep = (m < NPLANE) ? m : m - NPLANE;
    float e = err[(size_t)ep * HWn + i * Wn + j];
    double v = (double)(e * (f * f));
    for (int o = 32; o > 0; o >>= 1) v += __shfl_down(v, o, 64);
    if ((j & 63) == 0) partials[blk * 4 + (j >> 6)] = v;
}

// ---------------------------------------------------------------------------
// Kernel F: final reduction -> scalar (1024 threads)
// ---------------------------------------------------------------------------
__global__ void final_kernel(const double* __restrict__ partials,
                             const double* __restrict__ cepart,
                             float* __restrict__ out) {
    int tid = threadIdx.x;
    double a = 0.0, ce = 0.0;
    for (int idx = tid; idx < NROWBLK * 4; idx += 1024) a += partials[idx];
    for (int idx = tid; idx < 4096; idx += 1024) ce += cepart[idx];
    __shared__ double sa[1024], sc[1024];
    sa[tid] = a; sc[tid] = ce;
    __syncthreads();
    for (int s = 512; s > 0; s >>= 1) {
        if (tid < s) { sa[tid] += sa[tid + s]; sc[tid] += sc[tid + s]; }
        __syncthreads();
    }
    if (tid == 0) {
        double loss_sum = sa[0] / (double)NPIX;        // sum_c mean_{b,h,w}
        double cem = -sc[0] / (double)NPIX;            // ce
        double res = loss_sum / (double)Cn / (double)Bn / 3.0 + cem;
        out[0] = (float)res;
    }
}

// ---------------------------------------------------------------------------
extern "C" void kernel_launch(void* const* d_in, const int* in_sizes, int n_in,
                              void* d_out, int out_size, void* d_ws, size_t ws_size,
                              hipStream_t stream) {
    const float* pred  = (const float*)d_in[0];
    const int* target  = (const int*)d_in[1];
    float* out = (float*)d_out;
    char* ws = (char*)d_ws;

    // workspace layout (~40 MB total)
    unsigned int* maskw = (unsigned int*)ws;                         // 1 MB
    size_t off = (size_t)NPIX * 4;
    float* err = (float*)(ws + off);                                 // 12.6 MB
    off += (size_t)NPLANE * HWn * 4;
    unsigned short* gcol = (unsigned short*)(ws + off);              // 25.2 MB
    off += (size_t)NJOB * HWn * 2;
    unsigned int* fgflags = (unsigned int*)(ws + off);               // 8 u32 (pad 512)
    off += 512;
    unsigned int* blockOr = (unsigned int*)(ws + off);               // 4096*4
    off += 4096 * 4;
    double* partials = (double*)(ws + off);                          // 98304*8
    off += (size_t)NROWBLK * 4 * 8;
    double* cepart = (double*)(ws + off);                            // 4096*8

    masks_kernel<<<NPIX / 256, 256, 0, stream>>>(pred, target, maskw, err,
                                                 blockOr, cepart);
    colpass_kernel<<<NJOB * SEG + 1, 256, 0, stream>>>(maskw, blockOr, gcol, fgflags);
    rowpass_kernel<<<NROWBLK, 256, 0, stream>>>(gcol, err, fgflags, partials);
    final_kernel<<<1, 1024, 0, stream>>>(partials, cepart, out);
}

// Round 11
// 78.427 us; speedup vs baseline: 21.6681x; 1.2923x over previous
//
#include <hip/hip_runtime.h>
#include <math.h>

// Problem constants (match reference)
constexpr int Bn = 4, Cn = 12, Hn = 256, Wn = 256;
constexpr int HWn  = Hn * Wn;        // 65536
constexpr int NPIX = Bn * HWn;       // 262144
constexpr int NPLANE = Bn * Cn;      // 48 (b,c) planes
constexpr int NMASK = 2 * NPLANE;    // 96 masks (48 pred + 48 target)
constexpr int NJOB  = 2 * NMASK;     // 192 EDT jobs (edt(mask), edt(~mask))
constexpr float LARGEf = 1.0e6f;
constexpr unsigned short SENT = 65535;

// fgflags layout: [0..3] = pred fg bitmask per batch (bit c), [4..7] = tgt fg

// ---------------------------------------------------------------------------
// Kernel A: per-pixel softmax -> bit-packed masks word (bits 0..11 pred>0.5,
// bits 12..23 target one-hot), err = (prob-onehot)^2 per channel, CE partial
// per wave, per-wave OR word plain-stored (no contended atomics).
// ---------------------------------------------------------------------------
__global__ void masks_kernel(const float* __restrict__ pred,
                             const int* __restrict__ target,
                             unsigned int* __restrict__ maskw,
                             float* __restrict__ err,
                             unsigned int* __restrict__ blockOr,
                             double* __restrict__ cepart) {
    int pix = blockIdx.x * blockDim.x + threadIdx.x;   // grid = NPIX exactly
    int b = pix >> 16;            // / HW (each block lies within one b)
    int p = pix & (HWn - 1);
    float v[Cn];
    float mx = -3.4e38f;
#pragma unroll
    for (int c = 0; c < Cn; ++c) {
        v[c] = pred[(size_t)(b * Cn + c) * HWn + p];
        mx = fmaxf(mx, v[c]);
    }
    int t = target[pix];
    float raw_t = 0.f, s = 0.f;
#pragma unroll
    for (int c = 0; c < Cn; ++c) {
        if (c == t) raw_t = v[c];
        v[c] = expf(v[c] - mx);
        s += v[c];
    }
    unsigned word = 1u << (Cn + t);   // target one-hot bit
#pragma unroll
    for (int c = 0; c < Cn; ++c) {
        float prob = v[c] / s;
        int pb = (prob > 0.5f) ? 1 : 0;
        word |= (unsigned)pb << c;
        float oh = (c == t) ? 1.0f : 0.0f;
        float d = prob - oh;
        err[(size_t)(b * Cn + c) * HWn + p] = d * d;
    }
    maskw[pix] = word;
    float logp_t = raw_t - mx - logf(s);

    // wave-level OR + CE sum (no barriers), one plain store per wave
    unsigned worw = word;
    for (int o = 32; o > 0; o >>= 1) worw |= __shfl_down(worw, o, 64);
    double ced = (double)logp_t;
    for (int o = 32; o > 0; o >>= 1) ced += __shfl_down(ced, o, 64);
    int lane = threadIdx.x & 63, wv = threadIdx.x >> 6;
    if (lane == 0) {
        blockOr[blockIdx.x * 4 + wv] = worw;   // plain store, zero contention
        cepart[blockIdx.x * 4 + wv] = ced;
    }
}

__device__ __forceinline__ int mask_has_fg(const unsigned int* fgflags, int m) {
    int mm = (m < NPLANE) ? m : m - NPLANE;
    int b = mm / Cn, c = mm % Cn;
    unsigned fg = (m < NPLANE) ? fgflags[b] : fgflags[4 + b];
    return (fg >> c) & 1;
}

// ---------------------------------------------------------------------------
// Kernel C: segmented column pass (ungated; rowpass gates correctness).
// Block NJOB*SEG does the fgflags reduction (stream order covers the dep).
// ---------------------------------------------------------------------------
constexpr int SEG  = 4;
constexpr int SEGR = Hn / SEG;   // 64
constexpr int STRb = 68;         // LDS byte stride per thread (17 words, coprime banks)

__global__ void colpass_kernel(const unsigned int* __restrict__ maskw,
                               const unsigned int* __restrict__ blockOr,
                               unsigned short* __restrict__ gcol,
                               unsigned int* __restrict__ fgflags) {
    int blk = blockIdx.x;         // 0..768
    int tid = threadIdx.x;
    int lane = tid & 63, wv = tid >> 6;
    if (blk == NJOB * SEG) {
        unsigned acc = 0;
#pragma unroll
        for (int k = 0; k < 16; ++k) acc |= blockOr[wv * 1024 + k * 64 + lane];
        for (int o = 32; o > 0; o >>= 1) acc |= __shfl_down(acc, o, 64);
        if (lane == 0) {
            fgflags[wv] = acc & 0xFFFu;
            fgflags[4 + wv] = acc >> Cn;
        }
        return;
    }
    int jb = blk >> 2;            // job 0..191
    int cg = blk & 3;             // column group
    int m  = (jb < NMASK) ? jb : jb - NMASK;
    int mm = (m < NPLANE) ? m : m - NPLANE;
    int b = mm / Cn, c = mm % Cn;
    unsigned bit = (m < NPLANE) ? (unsigned)c : (unsigned)(Cn + c);
    unsigned inv = (jb < NMASK) ? 1u : 0u;  // feature = !maskbit for edt(mask)
    int s  = wv;                  // segment 0..3 (uniform per wave)
    int jl = lane;
    int j  = cg * 64 + jl;
    int r0 = s * SEGR;
    const unsigned int* mp = maskw + (size_t)b * HWn;
    unsigned short* gp = gcol + (size_t)jb * HWn;

    __shared__ unsigned char ldsF[256 * STRb];
    __shared__ unsigned char ldsB[256 * STRb];
    __shared__ float eF[256], eB[256];

    unsigned b0 = 0, b1 = 0;
    float cd = LARGEf;
    for (int i = 0; i < SEGR; ++i) {
        unsigned w = mp[(r0 + i) * Wn + j];
        unsigned f = ((w >> bit) & 1u) ^ inv;
        if (i < 32) b0 |= f << i; else b1 |= f << (i - 32);
        cd = f ? 0.f : fminf(cd + 1.f, LARGEf);
        ldsF[tid * STRb + i] = (unsigned char)fminf(cd, 255.f);   // <=63 or 255
    }
    eF[tid] = cd;
    cd = LARGEf;
    for (int i = SEGR - 1; i >= 0; --i) {
        unsigned f = ((i < 32) ? (b0 >> i) : (b1 >> (i - 32))) & 1u;
        cd = f ? 0.f : fminf(cd + 1.f, LARGEf);
        ldsB[tid * STRb + i] = (unsigned char)fminf(cd, 255.f);
    }
    eB[tid] = cd;
    __syncthreads();
    float x = LARGEf;                         // fwd inflow to my segment
    for (int sp = 0; sp < s; ++sp)
        x = fminf(eF[sp * 64 + jl], fminf(x + (float)SEGR, LARGEf));
    float y = LARGEf;                         // bwd inflow from below
    for (int sp = SEG - 1; sp > s; --sp)
        y = fminf(eB[sp * 64 + jl], fminf(y + (float)SEGR, LARGEf));
#pragma unroll 8
    for (int i = 0; i < SEGR; ++i) {
        unsigned char uf = ldsF[tid * STRb + i];
        unsigned char ub = ldsB[tid * STRb + i];
        float lf = (uf == 255u) ? LARGEf : (float)uf;
        float lb = (ub == 255u) ? LARGEf : (float)ub;
        float f = fminf(lf, fminf(x + (float)(i + 1), LARGEf));
        float w = fminf(lb, fminf(y + (float)(SEGR - i), LARGEf));
        float g = fminf(f, w);
        gp[(r0 + i) * Wn + j] = (g >= LARGEf) ? SENT : (unsigned short)g;
    }
}

// ---------------------------------------------------------------------------
// Kernel D (v2): WAVE-PER-ROW row pass fused with loss. Block = 4 rows of one
// plane (1 wave each, private LDS slice). Lane scans 4 columns (l+64g) in one
// fused loop: 4 independent fmin chains (ILP), exact (extra candidates for
// converged columns are >= k^2 >= their min). Stage via float4 b128 writes;
// one uniform barrier; f64 wave reduce -> ONE partial per row.
// ---------------------------------------------------------------------------
constexpr int RPAD = 256;
constexpr int NROWBLK = NMASK * Hn;   // 24576 row-jobs
constexpr int RPB = 4;                // rows per block (one per wave)

__device__ __forceinline__ void scan4(const float* __restrict__ base, float m[4]) {
    float k2 = 1.f;                    // k^2
    for (int k = 1; k < Wn; k += 2) {
        float mx = fmaxf(fmaxf(m[0], m[1]), fmaxf(m[2], m[3]));
        if (k2 >= mx) break;
        float k2b = k2 + (float)(2 * k + 1);   // (k+1)^2
#pragma unroll
        for (int g = 0; g < 4; ++g) {
            const float* p = base + 64 * g;
            m[g] = fminf(m[g], k2  + p[-k]);
            m[g] = fminf(m[g], k2b + p[-k - 1]);
            m[g] = fminf(m[g], k2  + p[k]);
            m[g] = fminf(m[g], k2b + p[k + 1]);
        }
        k2 = k2b + (float)(2 * k + 3);         // (k+2)^2
    }
}

__global__ void rowpass_kernel(const unsigned short* __restrict__ gcol,
                               const float* __restrict__ err,
                               const unsigned int* __restrict__ fgflags,
                               double* __restrict__ partials) {
    int blk = blockIdx.x;                 // 0..6143
    int tid = threadIdx.x;
    int lane = tid & 63, w = tid >> 6;
    int m = (blk * RPB) >> 8;             // plane (uniform: 4 rows never straddle)
    if (!mask_has_fg(fgflags, m)) {
        if (tid < RPB) partials[blk * RPB + tid] = 0.0;
        return;                           // uniform exit (no barrier divergence)
    }
    int job = blk * RPB + w;              // this wave's row-job
    int i = job & (Hn - 1);               // row
    const float X = 1e12f;                // == fl(1e6f*1e6f)
    __shared__ float lds[RPB][2][Wn + 2 * RPAD];
    float* rA = lds[w][0];
    float* rB = lds[w][1];

    // stage: lane covers cols 4*lane..4*lane+3 (8B gcol loads, b128 LDS writes)
    const unsigned short* rp = gcol + (size_t)m * HWn + i * Wn;            // edt(mask)
    const unsigned short* rq = gcol + (size_t)(m + NMASK) * HWn + i * Wn;  // edt(~mask)
    ushort4 ua = ((const ushort4*)rp)[lane];
    ushort4 ub = ((const ushort4*)rq)[lane];
    float4 fa, fb;
    fa.x = (ua.x == SENT) ? X : (float)((int)ua.x * (int)ua.x);
    fa.y = (ua.y == SENT) ? X : (float)((int)ua.y * (int)ua.y);
    fa.z = (ua.z == SENT) ? X : (float)((int)ua.z * (int)ua.z);
    fa.w = (ua.w == SENT) ? X : (float)((int)ua.w * (int)ua.w);
    fb.x = (ub.x == SENT) ? X : (float)((int)ub.x * (int)ub.x);
    fb.y = (ub.y == SENT) ? X : (float)((int)ub.y * (int)ub.y);
    fb.z = (ub.z == SENT) ? X : (float)((int)ub.z * (int)ub.z);
    fb.w = (ub.w == SENT) ? X : (float)((int)ub.w * (int)ub.w);
    float4 xv = make_float4(X, X, X, X);
    ((float4*)rA)[lane] = xv;                       // left pad [0..255]
    ((float4*)(rA + RPAD))[lane] = fa;              // data
    ((float4*)(rA + RPAD + Wn))[lane] = xv;         // right pad
    ((float4*)rB)[lane] = xv;
    ((float4*)(rB + RPAD))[lane] = fb;
    ((float4*)(rB + RPAD + Wn))[lane] = xv;
    __syncthreads();                      // uniform arrival (stage is data-indep)

    // scan: lane's 4 columns are lane + 64g
    float mA[4], mB[4];
#pragma unroll
    for (int g = 0; g < 4; ++g) {
        mA[g] = rA[RPAD + lane + 64 * g];
        mB[g] = rB[RPAD + lane + 64 * g];
    }
    scan4(rA + RPAD + lane, mA);
    scan4(rB + RPAD + lane, mB);

    // loss: field = sqrt(mA)+sqrt(mB); dot with err row
    int ep = (m < NPLANE) ? m : m - NPLANE;
    const float* epr = err + (size_t)ep * HWn + i * Wn;
    double v = 0.0;
#pragma unroll
    for (int g = 0; g < 4; ++g) {
        float f = sqrtf(mA[g]) + sqrtf(mB[g]);
        float e = epr[lane + 64 * g];
        v += (double)(e * (f * f));
    }
    for (int o = 32; o > 0; o >>= 1) v += __shfl_down(v, o, 64);
    if (lane == 0) partials[job] = v;
}

// ---------------------------------------------------------------------------
// Kernel F: final reduction -> scalar (1024 threads)
// ---------------------------------------------------------------------------
__global__ void final_kernel(const double* __restrict__ partials,
                             const double* __restrict__ cepart,
                             float* __restrict__ out) {
    int tid = threadIdx.x;
    double a = 0.0, ce = 0.0;
    for (int idx = tid; idx < NROWBLK; idx += 1024) a += partials[idx];
    for (int idx = tid; idx < 4096; idx += 1024) ce += cepart[idx];
    __shared__ double sa[1024], sc[1024];
    sa[tid] = a; sc[tid] = ce;
    __syncthreads();
    for (int s = 512; s > 0; s >>= 1) {
        if (tid < s) { sa[tid] += sa[tid + s]; sc[tid] += sc[tid + s]; }
        __syncthreads();
    }
    if (tid == 0) {
        double loss_sum = sa[0] / (double)NPIX;        // sum_c mean_{b,h,w}
        double cem = -sc[0] / (double)NPIX;            // ce
        double res = loss_sum / (double)Cn / (double)Bn / 3.0 + cem;
        out[0] = (float)res;
    }
}

// ---------------------------------------------------------------------------
extern "C" void kernel_launch(void* const* d_in, const int* in_sizes, int n_in,
                              void* d_out, int out_size, void* d_ws, size_t ws_size,
                              hipStream_t stream) {
    const float* pred  = (const float*)d_in[0];
    const int* target  = (const int*)d_in[1];
    float* out = (float*)d_out;
    char* ws = (char*)d_ws;

    // workspace layout (~40 MB total)
    unsigned int* maskw = (unsigned int*)ws;                         // 1 MB
    size_t off = (size_t)NPIX * 4;
    float* err = (float*)(ws + off);                                 // 12.6 MB
    off += (size_t)NPLANE * HWn * 4;
    unsigned short* gcol = (unsigned short*)(ws + off);              // 25.2 MB
    off += (size_t)NJOB * HWn * 2;
    unsigned int* fgflags = (unsigned int*)(ws + off);               // 8 u32 (pad 512)
    off += 512;
    unsigned int* blockOr = (unsigned int*)(ws + off);               // 4096*4
    off += 4096 * 4;
    double* partials = (double*)(ws + off);                          // 24576*8
    off += (size_t)NROWBLK * 8;
    double* cepart = (double*)(ws + off);                            // 4096*8

    masks_kernel<<<NPIX / 256, 256, 0, stream>>>(pred, target, maskw, err,
                                                 blockOr, cepart);
    colpass_kernel<<<NJOB * SEG + 1, 256, 0, stream>>>(maskw, blockOr, gcol, fgflags);
    rowpass_kernel<<<NROWBLK / RPB, 256, 0, stream>>>(gcol, err, fgflags, partials);
    final_kernel<<<1, 1024, 0, stream>>>(partials, cepart, out);
}